// Round 1
// baseline (904.412 us; speedup 1.0000x reference)
//
#include <hip/hip_runtime.h>

constexpr int N_NODES = 100000;
constexpr int N_EDGES = 1000000;
constexpr int IN_CH   = 64;
constexpr int OUT_CH  = 128;

// ---------------------------------------------------------------------------
// Scatter: agg[row] += w * x[col], 16 lanes per edge, float4 per lane.
// ---------------------------------------------------------------------------
__global__ __launch_bounds__(256) void gcn_scatter_kernel(
    const float* __restrict__ x,
    const int*   __restrict__ ei,    // [2, E] flat: ei[0..E) = row(dst), ei[E..2E) = col(src)
    const float* __restrict__ ew,
    float*       __restrict__ agg)   // [N, 64], pre-zeroed
{
    int tid = blockIdx.x * 256 + threadIdx.x;
    int e   = tid >> 4;
    if (e >= N_EDGES) return;
    int c4  = (tid & 15) << 2;       // channel offset 0,4,...,60

    int   dst = ei[e];
    int   src = ei[N_EDGES + e];
    float w   = ew[e];

    float4 v = *reinterpret_cast<const float4*>(x + (size_t)src * IN_CH + c4);
    float* ap = agg + (size_t)dst * IN_CH + c4;
    unsafeAtomicAdd(ap + 0, w * v.x);
    unsafeAtomicAdd(ap + 1, w * v.y);
    unsafeAtomicAdd(ap + 2, w * v.z);
    unsafeAtomicAdd(ap + 3, w * v.w);
}

// ---------------------------------------------------------------------------
// GEMM: out[N,128] = agg[N,64] @ W[128,64]^T + b
// 256 threads/block, 32 rows/block (100000 = 3125 * 32 exactly).
// Thread t: chT = t&31 -> channels chT+32j (j<4); rowT = t>>5 -> rows r0..r0+3.
// LDS stride 66 (even, non-pow2): ds_read_b64 conflict-light.
// ---------------------------------------------------------------------------
constexpr int LSTR = 66;

__global__ __launch_bounds__(256) void gcn_gemm_kernel(
    const float* __restrict__ agg,
    const float* __restrict__ W,     // [128, 64]
    const float* __restrict__ b,     // [128]
    float*       __restrict__ out)   // [N, 128]
{
    __shared__ float Wl[OUT_CH * LSTR];   // ~33 KB
    __shared__ float al[32 * LSTR];       // ~8.3 KB

    const int t = threadIdx.x;
    const int rbase = blockIdx.x * 32;

    // Stage W: 8192 floats, coalesced float4 reads.
    for (int i = t; i < OUT_CH * IN_CH / 4; i += 256) {
        float4 v = reinterpret_cast<const float4*>(W)[i];
        int c = i >> 4;               // (i*4)/64
        int k = (i & 15) << 2;
        float* p = &Wl[c * LSTR + k];
        p[0] = v.x; p[1] = v.y; p[2] = v.z; p[3] = v.w;
    }
    // Stage 32 agg rows: 2048 floats.
    for (int i = t; i < 32 * IN_CH / 4; i += 256) {
        float4 v = reinterpret_cast<const float4*>(agg + (size_t)rbase * IN_CH)[i];
        int r = i >> 4;
        int k = (i & 15) << 2;
        float* p = &al[r * LSTR + k];
        p[0] = v.x; p[1] = v.y; p[2] = v.z; p[3] = v.w;
    }
    __syncthreads();

    const int chT  = t & 31;
    const int r0   = (t >> 5) << 2;   // 0,4,...,28

    float acc[4][4];
    #pragma unroll
    for (int i = 0; i < 4; ++i)
        #pragma unroll
        for (int j = 0; j < 4; ++j)
            acc[i][j] = 0.f;

    #pragma unroll
    for (int k = 0; k < IN_CH; k += 2) {
        float2 wv[4], av[4];
        #pragma unroll
        for (int j = 0; j < 4; ++j)
            wv[j] = *reinterpret_cast<const float2*>(&Wl[(chT + 32 * j) * LSTR + k]);
        #pragma unroll
        for (int i = 0; i < 4; ++i)
            av[i] = *reinterpret_cast<const float2*>(&al[(r0 + i) * LSTR + k]);
        #pragma unroll
        for (int i = 0; i < 4; ++i)
            #pragma unroll
            for (int j = 0; j < 4; ++j)
                acc[i][j] += av[i].x * wv[j].x + av[i].y * wv[j].y;
    }

    #pragma unroll
    for (int j = 0; j < 4; ++j) {
        int   c  = chT + 32 * j;
        float bc = b[c];
        #pragma unroll
        for (int i = 0; i < 4; ++i) {
            int r = rbase + r0 + i;
            out[(size_t)r * OUT_CH + c] = acc[i][j] + bc;
        }
    }
}

extern "C" void kernel_launch(void* const* d_in, const int* in_sizes, int n_in,
                              void* d_out, int out_size, void* d_ws, size_t ws_size,
                              hipStream_t stream) {
    const float* x  = (const float*)d_in[0];
    const int*   ei = (const int*)  d_in[1];
    const float* ew = (const float*)d_in[2];
    const float* W  = (const float*)d_in[3];
    const float* b  = (const float*)d_in[4];
    float* out = (float*)d_out;
    float* agg = (float*)d_ws;                       // [N_NODES, IN_CH] fp32

    size_t agg_bytes = (size_t)N_NODES * IN_CH * sizeof(float);
    hipMemsetAsync(agg, 0, agg_bytes, stream);

    int scatter_threads = N_EDGES * 16;
    int scatter_grid    = (scatter_threads + 255) / 256;
    gcn_scatter_kernel<<<scatter_grid, 256, 0, stream>>>(x, ei, ew, agg);

    int gemm_grid = N_NODES / 32;                    // 3125, exact
    gcn_gemm_kernel<<<gemm_grid, 256, 0, stream>>>(agg, W, b, out);
}

// Round 2
// 206.279 us; speedup vs baseline: 4.3844x; 4.3844x over previous
//
#include <hip/hip_runtime.h>

constexpr int N_NODES = 100000;
constexpr int N_EDGES = 1000000;
constexpr int IN_CH   = 64;
constexpr int OUT_CH  = 128;

constexpr int SCAN_ELEMS  = 1024;                                  // per block
constexpr int SCAN_BLOCKS = (N_NODES + SCAN_ELEMS - 1) / SCAN_ELEMS; // 98

// ---------------------------------------------------------------------------
// Phase 1: histogram of destination degrees. 1M int atomics (vs 64M f32).
// ---------------------------------------------------------------------------
__global__ __launch_bounds__(256) void hist_kernel(
    const int* __restrict__ ei, int* __restrict__ count)
{
    int e = blockIdx.x * 256 + threadIdx.x;
    if (e < N_EDGES) atomicAdd(&count[ei[e]], 1);
}

// ---------------------------------------------------------------------------
// Phase 2: hierarchical exclusive scan of count[0..N) -> offset[0..N].
// ---------------------------------------------------------------------------
__global__ __launch_bounds__(256) void scanA_kernel(
    const int* __restrict__ count, int* __restrict__ offset,
    int* __restrict__ partials)
{
    __shared__ int ts[256];
    const int t    = threadIdx.x;
    const int base = blockIdx.x * SCAN_ELEMS + t * 4;

    int v[4], s = 0;
    #pragma unroll
    for (int j = 0; j < 4; ++j) {
        int i = base + j;
        v[j] = (i < N_NODES) ? count[i] : 0;
        s += v[j];
    }
    ts[t] = s;
    __syncthreads();
    for (int off = 1; off < 256; off <<= 1) {
        int add = (t >= off) ? ts[t - off] : 0;
        __syncthreads();
        ts[t] += add;
        __syncthreads();
    }
    int run = ts[t] - s;                      // exclusive prefix within block
    #pragma unroll
    for (int j = 0; j < 4; ++j) {
        int i = base + j;
        if (i < N_NODES) offset[i] = run;
        run += v[j];
    }
    if (t == 255) partials[blockIdx.x] = ts[255];
}

__global__ __launch_bounds__(128) void scanB_kernel(int* __restrict__ partials)
{
    __shared__ int ts[128];
    const int t = threadIdx.x;
    int v = (t < SCAN_BLOCKS) ? partials[t] : 0;
    ts[t] = v;
    __syncthreads();
    for (int off = 1; off < 128; off <<= 1) {
        int add = (t >= off) ? ts[t - off] : 0;
        __syncthreads();
        ts[t] += add;
        __syncthreads();
    }
    if (t < SCAN_BLOCKS) partials[t] = ts[t] - v;   // exclusive
}

__global__ __launch_bounds__(256) void scanC_kernel(
    int* __restrict__ offset, const int* __restrict__ partials)
{
    int i = blockIdx.x * 256 + threadIdx.x;
    if (i < N_NODES) offset[i] += partials[i >> 10];
    if (i == 0) offset[N_NODES] = N_EDGES;
}

// ---------------------------------------------------------------------------
// Phase 3: bin edges by destination. Uses count[dst] as a down-counter so no
// separate cursor array is needed (count ends at 0; re-zeroed next call).
// ---------------------------------------------------------------------------
__global__ __launch_bounds__(256) void bin_kernel(
    const int* __restrict__ ei, const float* __restrict__ ew,
    const int* __restrict__ offset, int* __restrict__ count,
    int2* __restrict__ bucket)
{
    int e = blockIdx.x * 256 + threadIdx.x;
    if (e >= N_EDGES) return;
    int   dst = ei[e];
    int   src = ei[N_EDGES + e];
    float w   = ew[e];
    int pos = atomicAdd(&count[dst], -1) - 1;       // deg-1 .. 0
    bucket[offset[dst] + pos] = make_int2(src, __float_as_int(w));
}

// ---------------------------------------------------------------------------
// Phase 4: atomic-free aggregation. 16 lanes per node, float4 per lane.
// ---------------------------------------------------------------------------
__global__ __launch_bounds__(256) void agg_kernel(
    const float* __restrict__ x, const int2* __restrict__ bucket,
    const int* __restrict__ offset, float* __restrict__ agg)
{
    int tid  = blockIdx.x * 256 + threadIdx.x;
    int node = tid >> 4;
    if (node >= N_NODES) return;
    int c4 = (tid & 15) << 2;

    int beg = offset[node];
    int end = offset[node + 1];

    float4 acc = make_float4(0.f, 0.f, 0.f, 0.f);
    for (int j = beg; j < end; ++j) {
        int2  eb = bucket[j];                       // broadcast across 16 lanes
        float w  = __int_as_float(eb.y);
        float4 v = *reinterpret_cast<const float4*>(x + (size_t)eb.x * IN_CH + c4);
        acc.x += w * v.x;
        acc.y += w * v.y;
        acc.z += w * v.z;
        acc.w += w * v.w;
    }
    *reinterpret_cast<float4*>(agg + (size_t)node * IN_CH + c4) = acc;
}

// ---------------------------------------------------------------------------
// Phase 5: out[N,128] = agg[N,64] @ W[128,64]^T + b  (unchanged from R1)
// ---------------------------------------------------------------------------
constexpr int LSTR = 66;

__global__ __launch_bounds__(256) void gcn_gemm_kernel(
    const float* __restrict__ agg,
    const float* __restrict__ W,
    const float* __restrict__ b,
    float*       __restrict__ out)
{
    __shared__ float Wl[OUT_CH * LSTR];
    __shared__ float al[32 * LSTR];

    const int t = threadIdx.x;
    const int rbase = blockIdx.x * 32;

    for (int i = t; i < OUT_CH * IN_CH / 4; i += 256) {
        float4 v = reinterpret_cast<const float4*>(W)[i];
        int c = i >> 4;
        int k = (i & 15) << 2;
        float* p = &Wl[c * LSTR + k];
        p[0] = v.x; p[1] = v.y; p[2] = v.z; p[3] = v.w;
    }
    for (int i = t; i < 32 * IN_CH / 4; i += 256) {
        float4 v = reinterpret_cast<const float4*>(agg + (size_t)rbase * IN_CH)[i];
        int r = i >> 4;
        int k = (i & 15) << 2;
        float* p = &al[r * LSTR + k];
        p[0] = v.x; p[1] = v.y; p[2] = v.z; p[3] = v.w;
    }
    __syncthreads();

    const int chT = t & 31;
    const int r0  = (t >> 5) << 2;

    float acc[4][4];
    #pragma unroll
    for (int i = 0; i < 4; ++i)
        #pragma unroll
        for (int j = 0; j < 4; ++j)
            acc[i][j] = 0.f;

    #pragma unroll
    for (int k = 0; k < IN_CH; k += 2) {
        float2 wv[4], av[4];
        #pragma unroll
        for (int j = 0; j < 4; ++j)
            wv[j] = *reinterpret_cast<const float2*>(&Wl[(chT + 32 * j) * LSTR + k]);
        #pragma unroll
        for (int i = 0; i < 4; ++i)
            av[i] = *reinterpret_cast<const float2*>(&al[(r0 + i) * LSTR + k]);
        #pragma unroll
        for (int i = 0; i < 4; ++i)
            #pragma unroll
            for (int j = 0; j < 4; ++j)
                acc[i][j] += av[i].x * wv[j].x + av[i].y * wv[j].y;
    }

    #pragma unroll
    for (int j = 0; j < 4; ++j) {
        int   c  = chT + 32 * j;
        float bc = b[c];
        #pragma unroll
        for (int i = 0; i < 4; ++i) {
            int r = rbase + r0 + i;
            out[(size_t)r * OUT_CH + c] = acc[i][j] + bc;
        }
    }
}

// ---------------------------------------------------------------------------
extern "C" void kernel_launch(void* const* d_in, const int* in_sizes, int n_in,
                              void* d_out, int out_size, void* d_ws, size_t ws_size,
                              hipStream_t stream) {
    const float* x  = (const float*)d_in[0];
    const int*   ei = (const int*)  d_in[1];
    const float* ew = (const float*)d_in[2];
    const float* W  = (const float*)d_in[3];
    const float* b  = (const float*)d_in[4];
    float* out = (float*)d_out;

    // Workspace layout (16B-aligned blocks)
    char* ws = (char*)d_ws;
    size_t off = 0;
    auto alloc = [&](size_t bytes) {
        char* p = ws + off;
        off += (bytes + 15) & ~size_t(15);
        return p;
    };
    float* agg      = (float*)alloc((size_t)N_NODES * IN_CH * sizeof(float)); // 25.6 MB
    int*   count    = (int*)  alloc((size_t)N_NODES * sizeof(int));           // 400 KB
    int*   offset   = (int*)  alloc((size_t)(N_NODES + 1) * sizeof(int));     // 400 KB
    int*   partials = (int*)  alloc(512 * sizeof(int));
    int2*  bucket   = (int2*) alloc((size_t)N_EDGES * sizeof(int2));          // 8 MB

    hipMemsetAsync(count, 0, (size_t)N_NODES * sizeof(int), stream);

    int egrid = (N_EDGES + 255) / 256;
    hist_kernel<<<egrid, 256, 0, stream>>>(ei, count);
    scanA_kernel<<<SCAN_BLOCKS, 256, 0, stream>>>(count, offset, partials);
    scanB_kernel<<<1, 128, 0, stream>>>(partials);
    scanC_kernel<<<(N_NODES + 255) / 256, 256, 0, stream>>>(offset, partials);
    bin_kernel<<<egrid, 256, 0, stream>>>(ei, ew, offset, count, bucket);

    int agrid = (N_NODES * 16 + 255) / 256;
    agg_kernel<<<agrid, 256, 0, stream>>>(x, bucket, offset, agg);

    gcn_gemm_kernel<<<N_NODES / 32, 256, 0, stream>>>(agg, W, b, out);
}